// Round 2
// baseline (1901.261 us; speedup 1.0000x reference)
//
#include <hip/hip_runtime.h>
#include <hip/hip_bf16.h>
#include <stdint.h>

// MultilayerPCN: bf16-MFMA, 64x64 tiles, in-block 8-way K-split, DIRECT
// global->VGPR fragment loads (no LDS staging, no global_load_lds DMA).
// NODES = [2048, 4096, 8192], B = 256, n_iters = 8 (hardcoded), LAMB = 0.5.
//
// Rationale (r1 post-mortem): both r0 and r1 ran at ~30 GB/s/CU of requested
// bytes regardless of geometry -> per-CU cap on the global_load_lds path.
// The LDS staging was a pure pass-through (frag offsets == global layout),
// so fragments are now loaded straight into VGPRs: per wave, 4-deep chunk
// pipeline (24 KB in flight), compiler-inserted vmcnt, 16 MFMA per chunk.
// LDS (64 KB) is used only for the 8-way partial reduction + fused epilogue,
// both kept verbatim from the verified r0 kernel.
//
// Per iteration, 2 launches:
//   phase1: [G2 = e2@W1 || G1 = e1@W0]     384 blocks x 512 thr
//   phase2: [G4 = T1@W1^T || G3 = T0@W0^T] 768 blocks x 512 thr

typedef short short8x __attribute__((ext_vector_type(8)));
typedef float float4x __attribute__((ext_vector_type(4)));
typedef unsigned short u16;
typedef u16 u16x8 __attribute__((ext_vector_type(8)));

static constexpr float LOSS_SCALE = 100.0f / 256.0f;

__device__ __forceinline__ u16 f2b(float x) {
    union { float f; uint32_t u; } v{x};
    uint32_t b = v.u + 0x7fffu + ((v.u >> 16) & 1u);
    return (u16)(b >> 16);
}

__device__ __forceinline__ float signf_(float x) {
    return (x > 0.f) ? 1.f : ((x < 0.f) ? -1.f : 0.f);
}

// ---------------- init / cast kernels ----------------
__global__ void k_zero(float* p, int n) {
    int i = blockIdx.x * blockDim.x + threadIdx.x;
    if (i < n) p[i] = 0.f;
}

// one pass: outN = bf16(in) (R x C), outT = bf16(in^T) (C x R)
__global__ __launch_bounds__(256) void k_cast_both(
    const float* __restrict__ in, u16* __restrict__ outN, u16* __restrict__ outT,
    int R, int C) {
    __shared__ float tile[32][33];
    int x = blockIdx.x * 32 + threadIdx.x;
#pragma unroll
    for (int k = 0; k < 32; k += 8) {
        int y = blockIdx.y * 32 + threadIdx.y + k;
        float v = in[(size_t)y * C + x];
        tile[threadIdx.y + k][threadIdx.x] = v;
        outN[(size_t)y * C + x] = f2b(v);
    }
    __syncthreads();
    int ox = blockIdx.y * 32 + threadIdx.x;
#pragma unroll
    for (int k = 0; k < 32; k += 8) {
        int oy = blockIdx.x * 32 + threadIdx.y + k;
        outT[(size_t)oy * R + ox] = f2b(tile[threadIdx.x][threadIdx.y + k]);
    }
}

__global__ void k_fill_v0(float* __restrict__ v0, const float* __restrict__ memory,
                          int n, int mask) {
    int i = blockIdx.x * blockDim.x + threadIdx.x;
    if (i < n) v0[i] = memory[i & mask];
}

__global__ void k_tanh(float* __restrict__ dst, const float* __restrict__ src, int n) {
    int i = blockIdx.x * blockDim.x + threadIdx.x;
    if (i < n) dst[i] = tanhf(src[i]);
}

__global__ void k_rowdot(const float* __restrict__ x, const float* __restrict__ W,
                         float* __restrict__ out, int K) {
    int i = blockIdx.x;
    const float* w = W + (size_t)i * K;
    float s = 0.f;
    for (int j = threadIdx.x; j < K; j += 256) s += x[j] * w[j];
    __shared__ float red[256];
    red[threadIdx.x] = s;
    __syncthreads();
    for (int st = 128; st > 0; st >>= 1) {
        if (threadIdx.x < st) red[threadIdx.x] += red[threadIdx.x + st];
        __syncthreads();
    }
    if (threadIdx.x == 0) out[i] = red[0];
}

__global__ void k_bcast_v1_e1(float* __restrict__ v1, float* __restrict__ e1,
                              u16* __restrict__ e1b,
                              const float* __restrict__ r1, int n, int mask) {
    int i = blockIdx.x * blockDim.x + threadIdx.x;
    if (i < n) { v1[i] = r1[i & mask]; e1[i] = 0.f; e1b[i] = 0; }
}

__global__ void k_e2_init(u16* __restrict__ e2b, const float* __restrict__ inp,
                          const float* __restrict__ r2, int n, int mask) {
    int i = blockIdx.x * blockDim.x + threadIdx.x;
    if (i < n) e2b[i] = f2b(inp[i] - r2[i & mask]);
}

// ---------------- direct-to-VGPR in-block K-split MFMA GEMM ----------------
struct GDR {
    const u16* A;       // [256, K] bf16 row-major
    const u16* Bt;      // [N, K]  bf16 row-major (B transposed)
    const float* x0;    // epilogue input 0
    const float* x1;    // epilogue input 1
    float* y0;          // fp32 state output
    u16* y0b;           // bf16 copy of y0 (EPI3)
    u16* y1b;           // bf16 aux output (T0b/T1b/e2b)
    float* loss;        // loss accumulator (EPI != 2)
    const float* lr;    // inf_lr (EPI1/2)
    int N, K, nCol;     // nCol = N/64; tiles = 4*nCol
};

template <int EPI>
__device__ void gemm_tile(const GDR& g, int tile, u16* stage, float* red8) {
    const int t = threadIdx.x;
    const int w = t >> 6, l = t & 63;
    const int lm = l & 15, lq = l >> 4;
    const int rowBlk = tile / g.nCol, colBlk = tile - rowBlk * g.nCol;
    const int row0 = rowBlk * 64, col0 = colBlk * 64;
    const int K = g.K;
    const int Ksl = K >> 3;          // this wave's K-slice length
    const int nCh = Ksl >> 5;        // chunks of 32 K-elements (8,16, or 32)

    // direct fragment pointers: lane l of frag i reads
    //   A[row0 + i*16 + lm][w*Ksl + c*32 + lq*8 .. +8)   (16B per lane)
    // wave footprint per frag-load: 16 rows x 64B contiguous -> coalesced.
    const u16* aP = g.A + (size_t)(row0 + lm) * K + w * Ksl + lq * 8;
    const u16* bP = g.Bt + (size_t)(col0 + lm) * K + w * Ksl + lq * 8;
    const size_t fstep = (size_t)16 * K;   // frag row stride (16 rows)

    float4x acc[4][4];
#pragma unroll
    for (int i = 0; i < 4; ++i)
#pragma unroll
        for (int j = 0; j < 4; ++j) acc[i][j] = (float4x)0.f;

#define LOADC(A_, B_, c) { \
    _Pragma("unroll") for (int i = 0; i < 4; ++i) { \
        A_[i] = *(const short8x*)(aP + (size_t)i * fstep + (size_t)(c) * 32); \
        B_[i] = *(const short8x*)(bP + (size_t)i * fstep + (size_t)(c) * 32); } }

#define MM(A_, B_) { \
    _Pragma("unroll") for (int i = 0; i < 4; ++i) \
    _Pragma("unroll") for (int j = 0; j < 4; ++j) \
        acc[i][j] = __builtin_amdgcn_mfma_f32_16x16x32_bf16(A_[i], B_[j], acc[i][j], 0, 0, 0); }

    // 4-deep software pipeline in registers (nCh is always a multiple of 4).
    short8x a0[4], b0[4], a1[4], b1[4], a2[4], b2[4], a3[4], b3[4];
    LOADC(a0, b0, 0); LOADC(a1, b1, 1); LOADC(a2, b2, 2); LOADC(a3, b3, 3);
    int c = 0;
    for (; c + 7 < nCh; c += 4) {
        MM(a0, b0); LOADC(a0, b0, c + 4);
        MM(a1, b1); LOADC(a1, b1, c + 5);
        MM(a2, b2); LOADC(a2, b2, c + 6);
        MM(a3, b3); LOADC(a3, b3, c + 7);
    }
    MM(a0, b0); MM(a1, b1); MM(a2, b2); MM(a3, b3);
#undef LOADC
#undef MM

    // ---- in-LDS tree reduction of 8 wave-partials ----
    // tile p = fp32 64x64 at stage + p*8192 u16 (16KB); frag (i,j) reg r maps to
    // row = i*16 + lq*4 + r, col = j*16 + lm  [C/D layout, m89-verified]
    float* T = (float*)stage;
    __syncthreads();
    if (w < 4) {
        float* tw = T + w * 4096;
#pragma unroll
        for (int i = 0; i < 4; ++i)
#pragma unroll
            for (int j = 0; j < 4; ++j)
#pragma unroll
                for (int r = 0; r < 4; ++r)
                    tw[(i * 16 + lq * 4 + r) * 64 + j * 16 + lm] = acc[i][j][r];
    }
    __syncthreads();
    if (w >= 4) {
        float* tw = T + (w - 4) * 4096;
#pragma unroll
        for (int i = 0; i < 4; ++i)
#pragma unroll
            for (int j = 0; j < 4; ++j)
#pragma unroll
                for (int r = 0; r < 4; ++r)
                    tw[(i * 16 + lq * 4 + r) * 64 + j * 16 + lm] += acc[i][j][r];
    }
    __syncthreads();
    if (w < 2) {        // tile w += tile w+2
        float* d = T + w * 4096;
        const float* s = T + (w + 2) * 4096;
#pragma unroll
        for (int q = 0; q < 16; ++q) {
            int o = l * 64 + q * 4;
            *(float4x*)(d + o) += *(const float4x*)(s + o);
        }
    }
    __syncthreads();
    if (w < 2) {        // tile0 += tile1, split between waves 0 and 1
        float* d = T + w * 2048;
        const float* s = T + 4096 + w * 2048;
#pragma unroll
        for (int q = 0; q < 8; ++q) {
            int o = l * 32 + q * 4;
            *(float4x*)(d + o) += *(const float4x*)(s + o);
        }
    }
    __syncthreads();

    // ---- fused epilogue: thread t handles row = t>>3, cols c8..c8+7 ----
    const int row = t >> 3, c8 = (t & 7) * 8;
    const size_t idx = (size_t)(row0 + row) * g.N + col0 + c8;
    float4x cv[2];
    cv[0] = *(const float4x*)(T + row * 64 + c8);
    cv[1] = *(const float4x*)(T + row * 64 + c8 + 4);

    float lr = 0.f;
    if (EPI == 1 || EPI == 2) lr = *g.lr;
    float lsum = 0.f;

    if (EPI == 1) {
        float4x vv[2], mm[2], nv[2]; u16x8 tb;
        vv[0] = *(const float4x*)(g.x0 + idx);       vv[1] = *(const float4x*)(g.x0 + idx + 4);
        mm[0] = *(const float4x*)(g.x1 + col0 + c8); mm[1] = *(const float4x*)(g.x1 + col0 + c8 + 4);
#pragma unroll
        for (int h = 0; h < 2; ++h)
#pragma unroll
            for (int e = 0; e < 4; ++e) {
                float v = vv[h][e], th = tanhf(v), td = 1.f - th * th;
                float d0 = (mm[h][e] - v) - 0.5f * signf_(v) + td * cv[h][e];
                float x = v + lr * d0;
                x = x > 0.f ? x : 0.f;
                nv[h][e] = x;
                tb[h * 4 + e] = f2b(tanhf(x));
                float ne0 = x - mm[h][e];
                lsum += ne0 * ne0;
            }
        *(float4x*)(g.y0 + idx) = nv[0];
        *(float4x*)(g.y0 + idx + 4) = nv[1];
        *(u16x8*)(g.y1b + idx) = tb;
    } else if (EPI == 2) {
        float4x vv[2], ee[2], nv[2]; u16x8 tb;
        vv[0] = *(const float4x*)(g.x0 + idx);     vv[1] = *(const float4x*)(g.x0 + idx + 4);
        ee[0] = *(const float4x*)(g.x1 + idx);     ee[1] = *(const float4x*)(g.x1 + idx + 4);
#pragma unroll
        for (int h = 0; h < 2; ++h)
#pragma unroll
            for (int e = 0; e < 4; ++e) {
                float v = vv[h][e], th = tanhf(v), td = 1.f - th * th;
                float x = v + lr * (-ee[h][e] + td * cv[h][e]);
                x = x > 0.f ? x : 0.f;
                nv[h][e] = x;
                tb[h * 4 + e] = f2b(tanhf(x));
            }
        *(float4x*)(g.y0 + idx) = nv[0];
        *(float4x*)(g.y0 + idx + 4) = nv[1];
        *(u16x8*)(g.y1b + idx) = tb;
    } else if (EPI == 3) {
        float4x vv[2], ne[2]; u16x8 nb;
        vv[0] = *(const float4x*)(g.x0 + idx);     vv[1] = *(const float4x*)(g.x0 + idx + 4);
#pragma unroll
        for (int h = 0; h < 2; ++h)
#pragma unroll
            for (int e = 0; e < 4; ++e) {
                float x = vv[h][e] - cv[h][e];
                ne[h][e] = x;
                nb[h * 4 + e] = f2b(x);
                lsum += x * x;
            }
        *(float4x*)(g.y0 + idx) = ne[0];
        *(float4x*)(g.y0 + idx + 4) = ne[1];
        *(u16x8*)(g.y0b + idx) = nb;
    } else {
        float4x vv[2]; u16x8 nb;
        vv[0] = *(const float4x*)(g.x0 + idx);     vv[1] = *(const float4x*)(g.x0 + idx + 4);
#pragma unroll
        for (int h = 0; h < 2; ++h)
#pragma unroll
            for (int e = 0; e < 4; ++e) {
                float x = vv[h][e] - cv[h][e];
                nb[h * 4 + e] = f2b(x);
                lsum += x * x;
            }
        *(u16x8*)(g.y1b + idx) = nb;
    }

    if (EPI != 2) {
#pragma unroll
        for (int off = 32; off > 0; off >>= 1) lsum += __shfl_down(lsum, off);
        if (l == 0) red8[w] = lsum;
        __syncthreads();
        if (t == 0) {
            float s = 0.f;
#pragma unroll
            for (int q = 0; q < 8; ++q) s += red8[q];
            atomicAdd(g.loss, s * LOSS_SCALE);
        }
    }
}

template <int EPIA, int EPIB>
__global__ __launch_bounds__(512, 2) void pcn_pair(GDR ga, GDR gb, int nA) {
    __shared__ u16 stage[32768];   // 64 KB: reduction tiles only
    __shared__ float red8[8];
    int bx = blockIdx.x;
    if (bx < nA) gemm_tile<EPIA>(ga, bx, stage, red8);
    else         gemm_tile<EPIB>(gb, bx - nA, stage, red8);
}

extern "C" void kernel_launch(void* const* d_in, const int* in_sizes, int n_in,
                              void* d_out, int out_size, void* d_ws, size_t ws_size,
                              hipStream_t stream)
{
    const float* batch_inp = (const float*)d_in[0]; // (256, 8192)
    const float* W0        = (const float*)d_in[1]; // (4096, 2048)
    const float* W1        = (const float*)d_in[2]; // (8192, 4096)
    const float* memory    = (const float*)d_in[3]; // (2048,)
    const float* lr_ptr    = (const float*)d_in[5]; // 0.05
    float* out = (float*)d_out;                     // 8 losses

    const int n0 = 2048, n1 = 4096, n2 = 8192, Bn = 256;

    // ---- workspace layout ----
    char* ws = (char*)d_ws;
    auto alloc_f = [&](size_t n) { float* p = (float*)ws; ws += n * 4; return p; };
    auto alloc_b = [&](size_t n) { u16* p = (u16*)ws; ws += n * 2; return p; };

    float* v0  = alloc_f((size_t)Bn * n0);
    float* v1  = alloc_f((size_t)Bn * n1);
    float* e1  = alloc_f((size_t)Bn * n1);
    u16*   e1b = alloc_b((size_t)Bn * n1);
    u16*   e2b = alloc_b((size_t)Bn * n2);
    u16*   T0b = alloc_b((size_t)Bn * n0);
    u16*   T1b = alloc_b((size_t)Bn * n1);
    u16*   W0b  = alloc_b((size_t)n1 * n0);   // (n1, n0) = W0 cast
    u16*   W0Tb = alloc_b((size_t)n0 * n1);   // (n0, n1) = W0^T cast
    u16*   W1b  = alloc_b((size_t)n2 * n1);   // (n2, n1) = W1 cast
    u16*   W1Tb = alloc_b((size_t)n1 * n2);   // (n1, n2) = W1^T cast
    float* tm = alloc_f(n0);
    float* r1 = alloc_f(n1);
    float* t1 = alloc_f(n1);
    float* r2 = alloc_f(n2);

    // ---- one-time init ----
    k_zero<<<1, 32, 0, stream>>>(out, 8);
    k_cast_both<<<dim3(n0 / 32, n1 / 32), dim3(32, 8), 0, stream>>>(W0, W0b, W0Tb, n1, n0);
    k_cast_both<<<dim3(n1 / 32, n2 / 32), dim3(32, 8), 0, stream>>>(W1, W1b, W1Tb, n2, n1);
    k_fill_v0<<<(Bn * n0) / 256, 256, 0, stream>>>(v0, memory, Bn * n0, n0 - 1);
    k_tanh<<<n0 / 256, 256, 0, stream>>>(tm, memory, n0);
    k_rowdot<<<n1, 256, 0, stream>>>(tm, W0, r1, n0);        // r1 = tanh(mem) @ W0^T
    k_tanh<<<n1 / 256, 256, 0, stream>>>(t1, r1, n1);
    k_bcast_v1_e1<<<(Bn * n1) / 256, 256, 0, stream>>>(v1, e1, e1b, r1, Bn * n1, n1 - 1);
    k_rowdot<<<n2, 256, 0, stream>>>(t1, W1, r2, n1);        // r2 = tanh(r1) @ W1^T
    k_e2_init<<<(Bn * n2) / 256, 256, 0, stream>>>(e2b, batch_inp, r2, Bn * n2, n2 - 1);

    // ---- 8 inference iterations ----
    for (int it = 0; it < 8; ++it) {
        float* loss = out + it;

        // phase 1: G2 (256 tiles) || G1 (128 tiles) — 384 blocks x 512 thr
        GDR g2{e2b, W1Tb, v1, e1, v1, nullptr, T1b, nullptr, lr_ptr, n1, n2, n1 / 64};
        GDR g1{e1b, W0Tb, v0, memory, v0, nullptr, T0b, loss, lr_ptr, n0, n1, n0 / 64};
        pcn_pair<2, 1><<<4 * (n1 / 64) + 4 * (n0 / 64), 512, 0, stream>>>(
            g2, g1, 4 * (n1 / 64));

        // phase 2: G4 (512 tiles) || G3 (256 tiles) — 768 blocks x 512 thr
        GDR g4{T1b, W1b, batch_inp, nullptr, nullptr, nullptr, e2b, loss, nullptr, n2, n1, n2 / 64};
        GDR g3{T0b, W0b, v1, nullptr, e1, e1b, nullptr, loss, nullptr, n1, n0, n1 / 64};
        pcn_pair<4, 3><<<4 * (n2 / 64) + 4 * (n1 / 64), 512, 0, stream>>>(
            g4, g3, 4 * (n2 / 64));
    }
}

// Round 3
// 1303.167 us; speedup vs baseline: 1.4590x; 1.4590x over previous
//
#include <hip/hip_runtime.h>
#include <hip/hip_bf16.h>
#include <stdint.h>

// MultilayerPCN: bf16-MFMA, split-K-across-blocks full-M partial GEMM + separate
// fused epilogue kernel. NODES = [2048, 4096, 8192], B = 256, n_iters = 8, LAMB = 0.5.
//
// r2 post-mortem: per-CU global-fetch rate is practically capped ~45-55 GB/s
// (m97/m201 flagship kernels sit there too); r0 had 640 MB/phase of requests at
// 1 block/CU (128 KB LDS). This version: block = 256 thr = 4 waves, computes a
// PARTIAL 256x64 tile over K/ks (wave = one 64-row block, Ksl=1024, nCh=32 for
// every block of every GEMM — perfectly uniform grid). B is read once per GEMM
// (full-M), requests drop to ~400 MB/phase, LDS = 64 KB -> 2 blocks/CU, and the
// proven private-staging vmcnt(8) barrier-free inner loop is unchanged.
// fp32 partials go to workspace; a separate epilogue kernel (stream-ordered, no
// cross-XCD coherence assumptions) sums kq partials + runs the fused node
// update / tanh / errors / loss.
//
// Per iteration, 4 launches:
//   gemm1: [G2p: 64cb x 8kq || G1p: 32cb x 4kq]  640 blocks x 256 thr
//   epi1 : [EPI2: 256 tiles || EPI1: 128 tiles]  384 blocks x 512 thr
//   gemm2: [G4p: 128cb x 4kq || G3p: 64cb x 2kq] 640 blocks x 256 thr
//   epi2 : [EPI4: 512 tiles || EPI3: 256 tiles]  768 blocks x 512 thr

typedef short short8x __attribute__((ext_vector_type(8)));
typedef float float4x __attribute__((ext_vector_type(4)));
typedef unsigned short u16;
typedef u16 u16x8 __attribute__((ext_vector_type(8)));

static constexpr float LOSS_SCALE = 100.0f / 256.0f;

__device__ __forceinline__ u16 f2b(float x) {
    union { float f; uint32_t u; } v{x};
    uint32_t b = v.u + 0x7fffu + ((v.u >> 16) & 1u);
    return (u16)(b >> 16);
}

__device__ __forceinline__ float signf_(float x) {
    return (x > 0.f) ? 1.f : ((x < 0.f) ? -1.f : 0.f);
}

__device__ __forceinline__ void gload_lds16(const void* g, void* lds) {
    __builtin_amdgcn_global_load_lds(
        (const __attribute__((address_space(1))) void*)g,
        (__attribute__((address_space(3))) void*)lds, 16, 0, 0);
}

// ---------------- init / cast kernels ----------------
__global__ void k_zero(float* p, int n) {
    int i = blockIdx.x * blockDim.x + threadIdx.x;
    if (i < n) p[i] = 0.f;
}

// one pass: outN = bf16(in) (R x C), outT = bf16(in^T) (C x R)
__global__ __launch_bounds__(256) void k_cast_both(
    const float* __restrict__ in, u16* __restrict__ outN, u16* __restrict__ outT,
    int R, int C) {
    __shared__ float tile[32][33];
    int x = blockIdx.x * 32 + threadIdx.x;
#pragma unroll
    for (int k = 0; k < 32; k += 8) {
        int y = blockIdx.y * 32 + threadIdx.y + k;
        float v = in[(size_t)y * C + x];
        tile[threadIdx.y + k][threadIdx.x] = v;
        outN[(size_t)y * C + x] = f2b(v);
    }
    __syncthreads();
    int ox = blockIdx.y * 32 + threadIdx.x;
#pragma unroll
    for (int k = 0; k < 32; k += 8) {
        int oy = blockIdx.x * 32 + threadIdx.y + k;
        outT[(size_t)oy * R + ox] = f2b(tile[threadIdx.x][threadIdx.y + k]);
    }
}

__global__ void k_fill_v0(float* __restrict__ v0, const float* __restrict__ memory,
                          int n, int mask) {
    int i = blockIdx.x * blockDim.x + threadIdx.x;
    if (i < n) v0[i] = memory[i & mask];
}

__global__ void k_tanh(float* __restrict__ dst, const float* __restrict__ src, int n) {
    int i = blockIdx.x * blockDim.x + threadIdx.x;
    if (i < n) dst[i] = tanhf(src[i]);
}

__global__ void k_rowdot(const float* __restrict__ x, const float* __restrict__ W,
                         float* __restrict__ out, int K) {
    int i = blockIdx.x;
    const float* w = W + (size_t)i * K;
    float s = 0.f;
    for (int j = threadIdx.x; j < K; j += 256) s += x[j] * w[j];
    __shared__ float red[256];
    red[threadIdx.x] = s;
    __syncthreads();
    for (int st = 128; st > 0; st >>= 1) {
        if (threadIdx.x < st) red[threadIdx.x] += red[threadIdx.x + st];
        __syncthreads();
    }
    if (threadIdx.x == 0) out[i] = red[0];
}

__global__ void k_bcast_v1_e1(float* __restrict__ v1, float* __restrict__ e1,
                              u16* __restrict__ e1b,
                              const float* __restrict__ r1, int n, int mask) {
    int i = blockIdx.x * blockDim.x + threadIdx.x;
    if (i < n) { v1[i] = r1[i & mask]; e1[i] = 0.f; e1b[i] = 0; }
}

__global__ void k_e2_init(u16* __restrict__ e2b, const float* __restrict__ inp,
                          const float* __restrict__ r2, int n, int mask) {
    int i = blockIdx.x * blockDim.x + threadIdx.x;
    if (i < n) e2b[i] = f2b(inp[i] - r2[i & mask]);
}

// ---------------- split-K partial GEMM (no barriers, no epilogue) ----------------
struct GGR {
    const u16* A;       // [256, K] bf16 row-major
    const u16* Bt;      // [N, K]  bf16 row-major (B transposed)
    float* Cp;          // fp32 partials [ks][256][N]
    int N, K, nCol, ks; // nCol = N/64; blocks = nCol*ks
};

__device__ void gemm_part(const GGR& g, int t, u16* stage) {
    const int tid = threadIdx.x;
    const int w = tid >> 6, l = tid & 63;
    const int lm = l & 15, lq = l >> 4;
    const int cb = t / g.ks, kq = t - cb * g.ks;   // block order cb*ks+kq: XCD ~ kq
    const int K = g.K;
    const int Ksl = K / g.ks;        // this block's K-slice (1024 for all GEMMs)
    const int nCh = Ksl >> 5;        // chunks of 32 (=32)
    const int col0 = cb * 64;

    // per-wave private staging: 16KB region; buf b: A at b*4096 u16, B at +2048
    u16* base = stage + (w << 13);
    const u16* aSrc = g.A + (size_t)(w * 64 + (l >> 2)) * K + kq * Ksl + (l & 3) * 8;
    const u16* bSrc = g.Bt + (size_t)(col0 + (l >> 2)) * K + kq * Ksl + (l & 3) * 8;
    const size_t rStep = (size_t)16 * K;   // 16 rows per staging issue

    int aoff[4];
#pragma unroll
    for (int i = 0; i < 4; ++i) aoff[i] = (i * 16 + lm) * 32 + lq * 8;

    float4x acc[4][4];
#pragma unroll
    for (int i = 0; i < 4; ++i)
#pragma unroll
        for (int j = 0; j < 4; ++j) acc[i][j] = (float4x)0.f;

#define ISSUE(c, b) { \
    u16* ab = base + (b) * 4096; \
    const u16* as = aSrc + (c) * 32; \
    const u16* bs = bSrc + (c) * 32; \
    gload_lds16(as, ab);             gload_lds16(as + rStep, ab + 512); \
    gload_lds16(as + 2*rStep, ab + 1024); gload_lds16(as + 3*rStep, ab + 1536); \
    gload_lds16(bs, ab + 2048);      gload_lds16(bs + rStep, ab + 2560); \
    gload_lds16(bs + 2*rStep, ab + 3072); gload_lds16(bs + 3*rStep, ab + 3584); }

#define COMPUTE(b) { \
    u16* ab = base + (b) * 4096; \
    short8x a[4], bb[4]; \
    _Pragma("unroll") for (int i = 0; i < 4; ++i) a[i] = *(const short8x*)(ab + aoff[i]); \
    _Pragma("unroll") for (int j = 0; j < 4; ++j) bb[j] = *(const short8x*)(ab + 2048 + aoff[j]); \
    _Pragma("unroll") for (int i = 0; i < 4; ++i) \
    _Pragma("unroll") for (int j = 0; j < 4; ++j) \
        acc[i][j] = __builtin_amdgcn_mfma_f32_16x16x32_bf16(a[i], bb[j], acc[i][j], 0, 0, 0); }

    ISSUE(0, 0);
    int c = 0;
    for (; c < nCh - 1; ++c) {
        __builtin_amdgcn_sched_barrier(0);
        ISSUE(c + 1, (c + 1) & 1);
        __builtin_amdgcn_sched_barrier(0);
        __builtin_amdgcn_s_waitcnt(0x0F78);   // vmcnt(8): chunk c staged
        __builtin_amdgcn_sched_barrier(0);
        COMPUTE(c & 1);
    }
    __builtin_amdgcn_sched_barrier(0);
    __builtin_amdgcn_s_waitcnt(0x0F70);       // vmcnt(0): last chunk staged
    __builtin_amdgcn_sched_barrier(0);
    COMPUTE(c & 1);
#undef ISSUE
#undef COMPUTE

    // store fp32 partial: frag (i,j) reg r -> row = i*16+lq*4+r, col = j*16+lm
    // [C/D layout, m89-verified]; Cp plane kq, rows w*64..w*64+63
    float* cp = g.Cp + ((size_t)(kq * 256 + w * 64) * g.N + col0);
#pragma unroll
    for (int i = 0; i < 4; ++i)
#pragma unroll
        for (int j = 0; j < 4; ++j)
#pragma unroll
            for (int r = 0; r < 4; ++r)
                cp[(size_t)(i * 16 + lq * 4 + r) * g.N + j * 16 + lm] = acc[i][j][r];
}

__global__ __launch_bounds__(256, 2) void pcn_gemm(GGR ga, GGR gb, int nA) {
    __shared__ u16 stage[32768];   // 64 KB -> 2 blocks/CU
    int bx = blockIdx.x;
    if (bx < nA) gemm_part(ga, bx, stage);
    else         gemm_part(gb, bx - nA, stage);
}

// ---------------- fused epilogue over kq-summed partials ----------------
struct EGR {
    const float* P;     // fp32 partials [ks][256][N]
    const float* x0;    // epilogue input 0
    const float* x1;    // epilogue input 1
    float* y0;          // fp32 state output
    u16* y0b;           // bf16 copy of y0 (EPI3)
    u16* y1b;           // bf16 aux output (T0b/T1b/e2b)
    float* loss;        // loss accumulator (EPI != 2)
    const float* lr;    // inf_lr (EPI1/2)
    int N, nCol, ks;    // tiles = 4*nCol
};

template <int EPI>
__device__ void epi_tile(const EGR& g, int tile, float* red8) {
    const int t = threadIdx.x;
    const int w = t >> 6, l = t & 63;
    const int rowBlk = tile / g.nCol, colBlk = tile - rowBlk * g.nCol;
    const int row0 = rowBlk * 64, col0 = colBlk * 64;
    const int row = t >> 3, c8 = (t & 7) * 8;
    const size_t idx = (size_t)(row0 + row) * g.N + col0 + c8;
    const size_t plane = (size_t)256 * g.N;

    // sum ks partials
    const float* p0 = g.P + idx;
    float4x cv[2];
    cv[0] = *(const float4x*)(p0);
    cv[1] = *(const float4x*)(p0 + 4);
    for (int q = 1; q < g.ks; ++q) {
        cv[0] += *(const float4x*)(p0 + (size_t)q * plane);
        cv[1] += *(const float4x*)(p0 + (size_t)q * plane + 4);
    }

    float lr = 0.f;
    if (EPI == 1 || EPI == 2) lr = *g.lr;
    float lsum = 0.f;

    if (EPI == 1) {
        float4x vv[2], mm[2], nv[2]; u16x8 tb;
        vv[0] = *(const float4x*)(g.x0 + idx);       vv[1] = *(const float4x*)(g.x0 + idx + 4);
        mm[0] = *(const float4x*)(g.x1 + col0 + c8); mm[1] = *(const float4x*)(g.x1 + col0 + c8 + 4);
#pragma unroll
        for (int h = 0; h < 2; ++h)
#pragma unroll
            for (int e = 0; e < 4; ++e) {
                float v = vv[h][e], th = tanhf(v), td = 1.f - th * th;
                float d0 = (mm[h][e] - v) - 0.5f * signf_(v) + td * cv[h][e];
                float x = v + lr * d0;
                x = x > 0.f ? x : 0.f;
                nv[h][e] = x;
                tb[h * 4 + e] = f2b(tanhf(x));
                float ne0 = x - mm[h][e];
                lsum += ne0 * ne0;
            }
        *(float4x*)(g.y0 + idx) = nv[0];
        *(float4x*)(g.y0 + idx + 4) = nv[1];
        *(u16x8*)(g.y1b + idx) = tb;
    } else if (EPI == 2) {
        float4x vv[2], ee[2], nv[2]; u16x8 tb;
        vv[0] = *(const float4x*)(g.x0 + idx);     vv[1] = *(const float4x*)(g.x0 + idx + 4);
        ee[0] = *(const float4x*)(g.x1 + idx);     ee[1] = *(const float4x*)(g.x1 + idx + 4);
#pragma unroll
        for (int h = 0; h < 2; ++h)
#pragma unroll
            for (int e = 0; e < 4; ++e) {
                float v = vv[h][e], th = tanhf(v), td = 1.f - th * th;
                float x = v + lr * (-ee[h][e] + td * cv[h][e]);
                x = x > 0.f ? x : 0.f;
                nv[h][e] = x;
                tb[h * 4 + e] = f2b(tanhf(x));
            }
        *(float4x*)(g.y0 + idx) = nv[0];
        *(float4x*)(g.y0 + idx + 4) = nv[1];
        *(u16x8*)(g.y1b + idx) = tb;
    } else if (EPI == 3) {
        float4x vv[2], ne[2]; u16x8 nb;
        vv[0] = *(const float4x*)(g.x0 + idx);     vv[1] = *(const float4x*)(g.x0 + idx + 4);
#pragma unroll
        for (int h = 0; h < 2; ++h)
#pragma unroll
            for (int e = 0; e < 4; ++e) {
                float x = vv[h][e] - cv[h][e];
                ne[h][e] = x;
                nb[h * 4 + e] = f2b(x);
                lsum += x * x;
            }
        *(float4x*)(g.y0 + idx) = ne[0];
        *(float4x*)(g.y0 + idx + 4) = ne[1];
        *(u16x8*)(g.y0b + idx) = nb;
    } else {
        float4x vv[2]; u16x8 nb;
        vv[0] = *(const float4x*)(g.x0 + idx);     vv[1] = *(const float4x*)(g.x0 + idx + 4);
#pragma unroll
        for (int h = 0; h < 2; ++h)
#pragma unroll
            for (int e = 0; e < 4; ++e) {
                float x = vv[h][e] - cv[h][e];
                nb[h * 4 + e] = f2b(x);
                lsum += x * x;
            }
        *(u16x8*)(g.y1b + idx) = nb;
    }

    if (EPI != 2) {
#pragma unroll
        for (int off = 32; off > 0; off >>= 1) lsum += __shfl_down(lsum, off);
        if (l == 0) red8[w] = lsum;
        __syncthreads();
        if (t == 0) {
            float s = 0.f;
#pragma unroll
            for (int q = 0; q < 8; ++q) s += red8[q];
            atomicAdd(g.loss, s * LOSS_SCALE);
        }
    }
}

template <int EPIA, int EPIB>
__global__ __launch_bounds__(512) void pcn_epi(EGR ga, EGR gb, int nA) {
    __shared__ float red8[8];
    int bx = blockIdx.x;
    if (bx < nA) epi_tile<EPIA>(ga, bx, red8);
    else         epi_tile<EPIB>(gb, bx - nA, red8);
}

extern "C" void kernel_launch(void* const* d_in, const int* in_sizes, int n_in,
                              void* d_out, int out_size, void* d_ws, size_t ws_size,
                              hipStream_t stream)
{
    const float* batch_inp = (const float*)d_in[0]; // (256, 8192)
    const float* W0        = (const float*)d_in[1]; // (4096, 2048)
    const float* W1        = (const float*)d_in[2]; // (8192, 4096)
    const float* memory    = (const float*)d_in[3]; // (2048,)
    const float* lr_ptr    = (const float*)d_in[5]; // 0.05
    float* out = (float*)d_out;                     // 8 losses

    const int n0 = 2048, n1 = 4096, n2 = 8192, Bn = 256;

    // ---- workspace layout ----
    char* ws = (char*)d_ws;
    auto alloc_f = [&](size_t n) { float* p = (float*)ws; ws += n * 4; return p; };
    auto alloc_b = [&](size_t n) { u16* p = (u16*)ws; ws += n * 2; return p; };

    float* v0  = alloc_f((size_t)Bn * n0);
    float* v1  = alloc_f((size_t)Bn * n1);
    float* e1  = alloc_f((size_t)Bn * n1);
    u16*   e1b = alloc_b((size_t)Bn * n1);
    u16*   e2b = alloc_b((size_t)Bn * n2);
    u16*   T0b = alloc_b((size_t)Bn * n0);
    u16*   T1b = alloc_b((size_t)Bn * n1);
    u16*   W0b  = alloc_b((size_t)n1 * n0);   // (n1, n0) = W0 cast
    u16*   W0Tb = alloc_b((size_t)n0 * n1);   // (n0, n1) = W0^T cast
    u16*   W1b  = alloc_b((size_t)n2 * n1);   // (n2, n1) = W1 cast
    u16*   W1Tb = alloc_b((size_t)n1 * n2);   // (n1, n2) = W1^T cast
    float* tm = alloc_f(n0);
    float* r1 = alloc_f(n1);
    float* t1 = alloc_f(n1);
    float* r2 = alloc_f(n2);
    // fp32 partial buffers (aliased across phases):
    //   CpA: 32 MB = max(8 x 256 x 4096, 4 x 256 x 8192)
    //   CpB:  8 MB = max(4 x 256 x 2048, 2 x 256 x 4096)
    float* CpA = alloc_f((size_t)8 * Bn * n1);
    float* CpB = alloc_f((size_t)4 * Bn * n0);

    // ---- one-time init ----
    k_zero<<<1, 32, 0, stream>>>(out, 8);
    k_cast_both<<<dim3(n0 / 32, n1 / 32), dim3(32, 8), 0, stream>>>(W0, W0b, W0Tb, n1, n0);
    k_cast_both<<<dim3(n1 / 32, n2 / 32), dim3(32, 8), 0, stream>>>(W1, W1b, W1Tb, n2, n1);
    k_fill_v0<<<(Bn * n0) / 256, 256, 0, stream>>>(v0, memory, Bn * n0, n0 - 1);
    k_tanh<<<n0 / 256, 256, 0, stream>>>(tm, memory, n0);
    k_rowdot<<<n1, 256, 0, stream>>>(tm, W0, r1, n0);        // r1 = tanh(mem) @ W0^T
    k_tanh<<<n1 / 256, 256, 0, stream>>>(t1, r1, n1);
    k_bcast_v1_e1<<<(Bn * n1) / 256, 256, 0, stream>>>(v1, e1, e1b, r1, Bn * n1, n1 - 1);
    k_rowdot<<<n2, 256, 0, stream>>>(t1, W1, r2, n1);        // r2 = tanh(r1) @ W1^T
    k_e2_init<<<(Bn * n2) / 256, 256, 0, stream>>>(e2b, batch_inp, r2, Bn * n2, n2 - 1);

    // ---- 8 inference iterations ----
    for (int it = 0; it < 8; ++it) {
        float* loss = out + it;

        // gemm1: G2p = e2@W1 partials (64cb x 8kq) || G1p = e1@W0 partials (32cb x 4kq)
        GGR g2{e2b, W1Tb, CpA, n1, n2, n1 / 64, 8};
        GGR g1{e1b, W0Tb, CpB, n0, n1, n0 / 64, 4};
        pcn_gemm<<<(n1 / 64) * 8 + (n0 / 64) * 4, 256, 0, stream>>>(g2, g1, (n1 / 64) * 8);

        // epi1: EPI2 over G2 (256 tiles) || EPI1 over G1 (128 tiles)
        EGR e2g{CpA, v1, e1, v1, nullptr, T1b, nullptr, lr_ptr, n1, n1 / 64, 8};
        EGR e1g{CpB, v0, memory, v0, nullptr, T0b, loss, lr_ptr, n0, n0 / 64, 4};
        pcn_epi<2, 1><<<4 * (n1 / 64) + 4 * (n0 / 64), 512, 0, stream>>>(
            e2g, e1g, 4 * (n1 / 64));

        // gemm2: G4p = T1@W1^T partials (128cb x 4kq) || G3p = T0@W0^T partials (64cb x 2kq)
        GGR g4{T1b, W1b, CpA, n2, n1, n2 / 64, 4};
        GGR g3{T0b, W0b, CpB, n1, n0, n1 / 64, 2};
        pcn_gemm<<<(n2 / 64) * 4 + (n1 / 64) * 2, 256, 0, stream>>>(g4, g3, (n2 / 64) * 4);

        // epi2: EPI4 over G4 (512 tiles) || EPI3 over G3 (256 tiles)
        EGR e4g{CpA, batch_inp, nullptr, nullptr, nullptr, e2b, loss, nullptr, n2, n2 / 64, 4};
        EGR e3g{CpB, v1, nullptr, e1, e1b, nullptr, loss, nullptr, n1, n1 / 64, 2};
        pcn_epi<4, 3><<<4 * (n2 / 64) + 4 * (n1 / 64), 512, 0, stream>>>(
            e4g, e3g, 4 * (n2 / 64));
    }
}